// Round 1
// baseline (315.851 us; speedup 1.0000x reference)
//
#include <hip/hip_runtime.h>
#include <stdint.h>

#define DEV static __device__ __forceinline__

typedef float f32x4 __attribute__((ext_vector_type(4)));
typedef __bf16 bf16x8 __attribute__((ext_vector_type(8)));
typedef unsigned short u16x8 __attribute__((ext_vector_type(8)));
typedef unsigned short u16;

#define B_ 2
#define L_ 2048
#define D_MODEL_ 1024
#define H_ 16
#define DH_ 64

DEV u16 f2bf(float f) {
  union { float f; uint32_t u; } v; v.f = f;
  uint32_t r = v.u + 0x7FFFu + ((v.u >> 16) & 1u);  // RNE
  return (u16)(r >> 16);
}

DEV f32x4 mfma16(bf16x8 a, bf16x8 b, f32x4 c) {
  return __builtin_amdgcn_mfma_f32_16x16x32_bf16(a, b, c, 0, 0, 0);
}

// async global->LDS, 16B per lane. LDS dest = wave-uniform base + lane*16.
DEV void gl_lds16(const void* g, void* l) {
  __builtin_amdgcn_global_load_lds(
      (const __attribute__((address_space(1))) unsigned int*)g,
      (__attribute__((address_space(3))) unsigned int*)l, 16, 0, 0);
}

// ---------------------------------------------------------------- cast f32->bf16
struct CastArgs {
  const float* src[7];
  u16* dst[7];
  int n8[7];
};

__global__ __launch_bounds__(256) void cast_kernel(CastArgs a) {
  const int z = blockIdx.z;
  const float* s = a.src[z];
  u16* d = a.dst[z];
  const int n8 = a.n8[z];
  const int stride = gridDim.x * blockDim.x;
  for (int i = blockIdx.x * blockDim.x + threadIdx.x; i < n8; i += stride) {
    const float4* sp = (const float4*)s + (size_t)i * 2;
    float4 x0 = sp[0], x1 = sp[1];
    u16x8 o;
    o[0] = f2bf(x0.x); o[1] = f2bf(x0.y); o[2] = f2bf(x0.z); o[3] = f2bf(x0.w);
    o[4] = f2bf(x1.x); o[5] = f2bf(x1.y); o[6] = f2bf(x1.z); o[7] = f2bf(x1.w);
    *((u16x8*)d + i) = o;
  }
}

// ---------------------------------------------------------------- GEMM  out = (X @ W^T + bias) * alpha
// X [4096,1024] bf16 row-major, W [1024,1024] bf16 row-major (N,K) -> NT GEMM.
// 128x128 tile, BK=64, 4 waves (each 64x64 = 4x4 frags of 16x16x32).
#define GM 4096
#define GN 1024
#define GK 1024

struct GemmArgs {
  const u16* X[3];
  const u16* W[3];
  const float* bias[3];
  void* out[3];
  float alpha[3];
};

template <bool F32OUT>
__global__ __launch_bounds__(256) void gemm_bt(GemmArgs g) {
  const int z = blockIdx.z;
  const u16* X = g.X[z];
  const u16* W = g.W[z];
  const float* bias = g.bias[z];
  const float alpha = g.alpha[z];
  const int m0 = blockIdx.y * 128, n0 = blockIdx.x * 128;

  __shared__ __align__(16) char smem[32 * 1024];
  char* As = smem;            // [128 rows][128B] XOR-swizzled by ((r&7)<<4)
  char* Bs = smem + 16 * 1024;

  const int tid = threadIdx.x;
  const int lane = tid & 63, w = tid >> 6;
  const int l15 = lane & 15, l4 = lane >> 4;
  const int wm = (w >> 1) * 64, wn = (w & 1) * 64;

  f32x4 acc[4][4];
#pragma unroll
  for (int i = 0; i < 4; ++i)
#pragma unroll
    for (int j = 0; j < 4; ++j) acc[i][j] = f32x4{0.f, 0.f, 0.f, 0.f};

  for (int ks = 0; ks < GK; ks += 64) {
    __syncthreads();  // previous tile's LDS reads done
    // stage A,B: 16 chunks of 1KB each; wave handles chunks w, w+4, w+8, w+12.
    // linear LDS dest + pre-swizzled global source (XOR within 128B rows).
    for (int c = w; c < 16; c += 4) {
      int r = c * 8 + (lane >> 3);
      int j = lane & 7;
      int sj = j ^ (r & 7);
      gl_lds16((const char*)(X + (size_t)(m0 + r) * GK + ks) + sj * 16, As + c * 1024);
      gl_lds16((const char*)(W + (size_t)(n0 + r) * GK + ks) + sj * 16, Bs + c * 1024);
    }
    __syncthreads();  // vmcnt drained by compiler before barrier
#pragma unroll
    for (int ksub = 0; ksub < 2; ++ksub) {
      bf16x8 af[4], bfr[4];
#pragma unroll
      for (int mf = 0; mf < 4; ++mf) {
        int r = wm + mf * 16 + l15;
        int j16 = ksub * 4 + l4;
        af[mf] = *(const bf16x8*)(As + r * 128 + ((j16 ^ (r & 7)) * 16));
      }
#pragma unroll
      for (int nf = 0; nf < 4; ++nf) {
        int r = wn + nf * 16 + l15;
        int j16 = ksub * 4 + l4;
        bfr[nf] = *(const bf16x8*)(Bs + r * 128 + ((j16 ^ (r & 7)) * 16));
      }
#pragma unroll
      for (int mf = 0; mf < 4; ++mf)
#pragma unroll
        for (int nf = 0; nf < 4; ++nf) acc[mf][nf] = mfma16(af[mf], bfr[nf], acc[mf][nf]);
    }
  }

  // epilogue: C[m][n], row = 4*l4 + reg, col = l15 (verified layout)
#pragma unroll
  for (int nf = 0; nf < 4; ++nf) {
    int n = n0 + wn + nf * 16 + l15;
    float bv = bias[n];
#pragma unroll
    for (int mf = 0; mf < 4; ++mf) {
#pragma unroll
      for (int r = 0; r < 4; ++r) {
        int m = m0 + wm + mf * 16 + l4 * 4 + r;
        float val = (acc[mf][nf][r] + bv) * alpha;
        if (F32OUT)
          ((float*)g.out[z])[(size_t)m * GN + n] = val;
        else
          ((u16*)g.out[z])[(size_t)m * GN + n] = f2bf(val);
      }
    }
  }
}

// ---------------------------------------------------------------- V transpose
// Vp [B,L,D] bf16 -> VT [B,H,DH,L] bf16
__global__ __launch_bounds__(256) void transpose_v(const u16* Vp, u16* VT) {
  const int l0 = blockIdx.x * 64;
  const int h = blockIdx.y, b = blockIdx.z;
  __shared__ __align__(16) char sm[64 * 128];
  const int tid = threadIdx.x;
  for (int s = tid; s < 512; s += 256) {
    int r = s >> 3, j = s & 7;
    const u16* src = Vp + ((size_t)(b * L_ + l0 + r) * D_MODEL_ + h * DH_ + j * 8);
    u16x8 v = *(const u16x8*)src;
    *(u16x8*)(sm + r * 128 + ((j ^ (r & 7)) * 16)) = v;
  }
  __syncthreads();
  for (int s = tid; s < 512; s += 256) {
    int d = s >> 3, jc = s & 7;
    u16x8 v;
#pragma unroll
    for (int e = 0; e < 8; ++e) {
      int r = jc * 8 + e;
      v[e] = *(const u16*)(sm + r * 128 + (((d >> 3) ^ (r & 7)) * 16) + (d & 7) * 2);
    }
    u16* dst = VT + ((size_t)((b * H_ + h) * DH_ + d) * L_ + l0 + jc * 8);
    *(u16x8*)dst = v;
  }
}

// ---------------------------------------------------------------- fused attention
// Per (b,h,64-row q-tile): pass1 online row max/sum (S recomputed, not stored),
// pass2 recompute S, write P=softmax to d_out (nontemporal f32), P->LDS bf16,
// ctx += P @ V via MFMA (V pre-transposed so PV is NT).
__global__ __launch_bounds__(256) void attn_kernel(const u16* Qp, const u16* Kp,
                                                   const u16* VT, float* attn,
                                                   u16* ctx) {
  const int q0 = blockIdx.x * 64;
  const int h = blockIdx.y, b = blockIdx.z;
  const int tid = threadIdx.x, lane = tid & 63, w = tid >> 6;
  const int l15 = lane & 15, l4 = lane >> 4;

  __shared__ __align__(16) char smem[4 * 8192];
  char* Qs = smem;
  char* Ks = smem + 8192;
  char* Vs = smem + 16384;
  char* Ps = smem + 24576;

  const u16* Qbase = Qp + ((size_t)(b * L_ + q0) * D_MODEL_ + h * DH_);
  const u16* Kbase = Kp + ((size_t)(b * L_) * D_MODEL_ + h * DH_);
  const u16* VTb = VT + ((size_t)((b * H_ + h) * DH_) * L_);
  float* attnb = attn + ((size_t)(b * H_ + h)) * L_ * L_;

  // stage Q tile (8KB), swizzled
  for (int c = w; c < 8; c += 4) {
    int r = c * 8 + (lane >> 3), j = lane & 7, sj = j ^ (r & 7);
    gl_lds16((const char*)(Qbase + (size_t)r * D_MODEL_) + sj * 16, Qs + c * 1024);
  }
  __syncthreads();
  // hoist this wave's Q A-fragments (rows 16w..16w+15)
  bf16x8 qa[2];
#pragma unroll
  for (int ksub = 0; ksub < 2; ++ksub) {
    int r = w * 16 + l15;
    int j16 = ksub * 4 + l4;
    qa[ksub] = *(const bf16x8*)(Qs + r * 128 + ((j16 ^ (r & 7)) * 16));
  }

  float mrun[4], ssum[4];
#pragma unroll
  for (int r = 0; r < 4; ++r) { mrun[r] = -3.0e38f; ssum[r] = 0.f; }

  // ---- pass 1: running max + sum
  for (int t = 0; t < 32; ++t) {
    __syncthreads();
    int c0 = t * 64;
    for (int c = w; c < 8; c += 4) {
      int r = c * 8 + (lane >> 3), j = lane & 7, sj = j ^ (r & 7);
      gl_lds16((const char*)(Kbase + (size_t)(c0 + r) * D_MODEL_) + sj * 16, Ks + c * 1024);
    }
    __syncthreads();
    f32x4 s[4];
#pragma unroll
    for (int nf = 0; nf < 4; ++nf) s[nf] = f32x4{0.f, 0.f, 0.f, 0.f};
#pragma unroll
    for (int ksub = 0; ksub < 2; ++ksub) {
      int j16 = ksub * 4 + l4;
      bf16x8 kb[4];
#pragma unroll
      for (int nf = 0; nf < 4; ++nf) {
        int r = nf * 16 + l15;
        kb[nf] = *(const bf16x8*)(Ks + r * 128 + ((j16 ^ (r & 7)) * 16));
      }
#pragma unroll
      for (int nf = 0; nf < 4; ++nf) s[nf] = mfma16(qa[ksub], kb[nf], s[nf]);
    }
#pragma unroll
    for (int r = 0; r < 4; ++r) {
      float tm = fmaxf(fmaxf(s[0][r], s[1][r]), fmaxf(s[2][r], s[3][r]));
      tm = fmaxf(tm, __shfl_xor(tm, 1));
      tm = fmaxf(tm, __shfl_xor(tm, 2));
      tm = fmaxf(tm, __shfl_xor(tm, 4));
      tm = fmaxf(tm, __shfl_xor(tm, 8));
      float mn = fmaxf(mrun[r], tm);
      float es = __expf(s[0][r] - mn) + __expf(s[1][r] - mn) +
                 __expf(s[2][r] - mn) + __expf(s[3][r] - mn);
      es += __shfl_xor(es, 1);
      es += __shfl_xor(es, 2);
      es += __shfl_xor(es, 4);
      es += __shfl_xor(es, 8);
      ssum[r] = ssum[r] * __expf(mrun[r] - mn) + es;
      mrun[r] = mn;
    }
  }

  float inv[4];
#pragma unroll
  for (int r = 0; r < 4; ++r) inv[r] = 1.f / ssum[r];

  f32x4 cacc[4];
#pragma unroll
  for (int i = 0; i < 4; ++i) cacc[i] = f32x4{0.f, 0.f, 0.f, 0.f};

  // ---- pass 2: P out + PV
  for (int t = 0; t < 32; ++t) {
    __syncthreads();
    int c0 = t * 64;
    for (int c = w; c < 8; c += 4) {
      int r = c * 8 + (lane >> 3), j = lane & 7, sj = j ^ (r & 7);
      gl_lds16((const char*)(Kbase + (size_t)(c0 + r) * D_MODEL_) + sj * 16, Ks + c * 1024);
      gl_lds16((const char*)(VTb + (size_t)r * L_ + c0) + sj * 16, Vs + c * 1024);
    }
    __syncthreads();
    f32x4 s[4];
#pragma unroll
    for (int nf = 0; nf < 4; ++nf) s[nf] = f32x4{0.f, 0.f, 0.f, 0.f};
#pragma unroll
    for (int ksub = 0; ksub < 2; ++ksub) {
      int j16 = ksub * 4 + l4;
      bf16x8 kb[4];
#pragma unroll
      for (int nf = 0; nf < 4; ++nf) {
        int r = nf * 16 + l15;
        kb[nf] = *(const bf16x8*)(Ks + r * 128 + ((j16 ^ (r & 7)) * 16));
      }
#pragma unroll
      for (int nf = 0; nf < 4; ++nf) s[nf] = mfma16(qa[ksub], kb[nf], s[nf]);
    }
    // P = exp(S-m)/sum ; write f32 to d_out (streaming) and bf16 to LDS
#pragma unroll
    for (int nf = 0; nf < 4; ++nf) {
#pragma unroll
      for (int r = 0; r < 4; ++r) {
        int row = w * 16 + l4 * 4 + r;
        int col = nf * 16 + l15;
        float p = __expf(s[nf][r] - mrun[r]) * inv[r];
        __builtin_nontemporal_store(p, attnb + (size_t)(q0 + row) * L_ + c0 + col);
        *(u16*)(Ps + row * 128 + ((((col >> 3) ^ (row & 7))) * 16) + (col & 7) * 2) =
            f2bf(p);
      }
    }
    // PV: ctx[q][d] += sum_kk P[q][kk] * VT[d][kk]
#pragma unroll
    for (int ksub = 0; ksub < 2; ++ksub) {
      int j16 = ksub * 4 + l4;
      int rr = w * 16 + l15;
      bf16x8 pa = *(const bf16x8*)(Ps + rr * 128 + ((j16 ^ (rr & 7)) * 16));
#pragma unroll
      for (int df = 0; df < 4; ++df) {
        int r = df * 16 + l15;
        bf16x8 vb = *(const bf16x8*)(Vs + r * 128 + ((j16 ^ (r & 7)) * 16));
        cacc[df] = mfma16(pa, vb, cacc[df]);
      }
    }
  }

  // ctx write (bf16)
#pragma unroll
  for (int df = 0; df < 4; ++df) {
#pragma unroll
    for (int r = 0; r < 4; ++r) {
      int row = q0 + w * 16 + l4 * 4 + r;
      int col = h * DH_ + df * 16 + l15;
      ctx[(size_t)(b * L_ + row) * D_MODEL_ + col] = f2bf(cacc[df][r]);
    }
  }
}

// ---------------------------------------------------------------- launch
extern "C" void kernel_launch(void* const* d_in, const int* in_sizes, int n_in,
                              void* d_out, int out_size, void* d_ws, size_t ws_size,
                              hipStream_t stream) {
  const float* q = (const float*)d_in[0];
  const float* k = (const float*)d_in[1];
  const float* v = (const float*)d_in[2];
  const float* w_q = (const float*)d_in[3];
  const float* b_q = (const float*)d_in[4];
  const float* w_k = (const float*)d_in[5];
  const float* b_k = (const float*)d_in[6];
  const float* w_v = (const float*)d_in[7];
  const float* b_v = (const float*)d_in[8];
  const float* w_o = (const float*)d_in[9];
  const float* b_o = (const float*)d_in[10];

  float* out = (float*)d_out;
  float* attn = (float*)d_out + (size_t)B_ * L_ * D_MODEL_;  // +4194304

  const size_t MB = 1u << 20;
  char* ws = (char*)d_ws;
  u16* qb = (u16*)(ws + 0 * MB);    // 8MB, reused as VT afterwards
  u16* kb = (u16*)(ws + 8 * MB);    // 8MB, reused as ctx afterwards
  u16* vb = (u16*)(ws + 16 * MB);   // 8MB
  u16* wqb = (u16*)(ws + 24 * MB);  // 2MB
  u16* wkb = (u16*)(ws + 26 * MB);
  u16* wvb = (u16*)(ws + 28 * MB);
  u16* wob = (u16*)(ws + 30 * MB);
  u16* Qp = (u16*)(ws + 32 * MB);  // 8MB
  u16* Kp = (u16*)(ws + 40 * MB);  // 8MB
  u16* Vp = (u16*)(ws + 48 * MB);  // 8MB
  u16* VT = qb;
  u16* ctx = kb;

  // 1. cast everything to bf16
  CastArgs ca;
  ca.src[0] = q;   ca.dst[0] = qb;  ca.n8[0] = (B_ * L_ * D_MODEL_) / 8;
  ca.src[1] = k;   ca.dst[1] = kb;  ca.n8[1] = (B_ * L_ * D_MODEL_) / 8;
  ca.src[2] = v;   ca.dst[2] = vb;  ca.n8[2] = (B_ * L_ * D_MODEL_) / 8;
  ca.src[3] = w_q; ca.dst[3] = wqb; ca.n8[3] = (D_MODEL_ * D_MODEL_) / 8;
  ca.src[4] = w_k; ca.dst[4] = wkb; ca.n8[4] = (D_MODEL_ * D_MODEL_) / 8;
  ca.src[5] = w_v; ca.dst[5] = wvb; ca.n8[5] = (D_MODEL_ * D_MODEL_) / 8;
  ca.src[6] = w_o; ca.dst[6] = wob; ca.n8[6] = (D_MODEL_ * D_MODEL_) / 8;
  cast_kernel<<<dim3(1024, 1, 7), 256, 0, stream>>>(ca);

  // 2. QKV projections (alpha=1/8 folded into Q)
  GemmArgs ga;
  ga.X[0] = qb;  ga.W[0] = wqb; ga.bias[0] = b_q; ga.out[0] = Qp; ga.alpha[0] = 0.125f;
  ga.X[1] = kb;  ga.W[1] = wkb; ga.bias[1] = b_k; ga.out[1] = Kp; ga.alpha[1] = 1.f;
  ga.X[2] = vb;  ga.W[2] = wvb; ga.bias[2] = b_v; ga.out[2] = Vp; ga.alpha[2] = 1.f;
  gemm_bt<false><<<dim3(8, 32, 3), 256, 0, stream>>>(ga);

  // 3. V transpose
  transpose_v<<<dim3(32, 16, 2), 256, 0, stream>>>(Vp, VT);

  // 4. fused attention: attn out + ctx
  attn_kernel<<<dim3(32, 16, 2), 256, 0, stream>>>(Qp, Kp, VT, attn, ctx);

  // 5. output projection
  GemmArgs go;
  go.X[0] = ctx; go.W[0] = wob; go.bias[0] = b_o; go.out[0] = out; go.alpha[0] = 1.f;
  go.X[1] = ctx; go.W[1] = wob; go.bias[1] = b_o; go.out[1] = out; go.alpha[1] = 1.f;
  go.X[2] = ctx; go.W[2] = wob; go.bias[2] = b_o; go.out[2] = out; go.alpha[2] = 1.f;
  gemm_bt<true><<<dim3(8, 32, 1), 256, 0, stream>>>(go);
}

// Round 2
// 277.642 us; speedup vs baseline: 1.1376x; 1.1376x over previous
//
#include <hip/hip_runtime.h>
#include <stdint.h>

#define DEV static __device__ __forceinline__

typedef float f32x4 __attribute__((ext_vector_type(4)));
typedef __bf16 bf16x8 __attribute__((ext_vector_type(8)));
typedef unsigned short u16x8 __attribute__((ext_vector_type(8)));
typedef unsigned short u16x4 __attribute__((ext_vector_type(4)));
typedef unsigned short u16;

#define B_ 2
#define L_ 2048
#define D_MODEL_ 1024
#define H_ 16
#define DH_ 64

DEV u16 f2bf(float f) {
  union { float f; uint32_t u; } v; v.f = f;
  uint32_t r = v.u + 0x7FFFu + ((v.u >> 16) & 1u);  // RNE
  return (u16)(r >> 16);
}

DEV f32x4 mfma16(bf16x8 a, bf16x8 b, f32x4 c) {
  return __builtin_amdgcn_mfma_f32_16x16x32_bf16(a, b, c, 0, 0, 0);
}

// async global->LDS, 16B per lane. LDS dest = wave-uniform base + lane*16.
DEV void gl_lds16(const void* g, void* l) {
  __builtin_amdgcn_global_load_lds(
      (const __attribute__((address_space(1))) unsigned int*)g,
      (__attribute__((address_space(3))) unsigned int*)l, 16, 0, 0);
}

// ---------------------------------------------------------------- cast f32->bf16
struct CastArgs {
  const float* src[7];
  u16* dst[7];
  int n8[7];
};

__global__ __launch_bounds__(256) void cast_kernel(CastArgs a) {
  const int z = blockIdx.z;
  const float* s = a.src[z];
  u16* d = a.dst[z];
  const int n8 = a.n8[z];
  const int stride = gridDim.x * blockDim.x;
  for (int i = blockIdx.x * blockDim.x + threadIdx.x; i < n8; i += stride) {
    const float4* sp = (const float4*)s + (size_t)i * 2;
    float4 x0 = sp[0], x1 = sp[1];
    u16x8 o;
    o[0] = f2bf(x0.x); o[1] = f2bf(x0.y); o[2] = f2bf(x0.z); o[3] = f2bf(x0.w);
    o[4] = f2bf(x1.x); o[5] = f2bf(x1.y); o[6] = f2bf(x1.z); o[7] = f2bf(x1.w);
    *((u16x8*)d + i) = o;
  }
}

// ---------------------------------------------------------------- GEMM  out = (X @ W^T + bias) * alpha
// X [4096,1024] bf16 row-major, W [1024,1024] bf16 row-major (N,K) -> NT GEMM.
// 128x128 tile, BK=64, 4 waves (each 64x64 = 4x4 frags of 16x16x32).
// mode 0: bf16 row-major out; mode 1: f32 row-major out; mode 2: VT bf16 out [B][H][DH][L]
#define GM 4096
#define GN 1024
#define GK 1024

struct GemmArgs {
  const u16* X[3];
  const u16* W[3];
  const float* bias[3];
  void* out[3];
  float alpha[3];
  int mode[3];
};

__global__ __launch_bounds__(256) void gemm_bt(GemmArgs g) {
  const int z = blockIdx.z;
  const u16* X = g.X[z];
  const u16* W = g.W[z];
  const float* bias = g.bias[z];
  const float alpha = g.alpha[z];
  const int mode = g.mode[z];
  const int m0 = blockIdx.y * 128, n0 = blockIdx.x * 128;

  __shared__ __align__(16) char smem[32 * 1024];
  char* As = smem;            // [128 rows][128B] XOR-swizzled by ((r&7)<<4)
  char* Bs = smem + 16 * 1024;

  const int tid = threadIdx.x;
  const int lane = tid & 63, w = tid >> 6;
  const int l15 = lane & 15, l4 = lane >> 4;
  const int wm = (w >> 1) * 64, wn = (w & 1) * 64;

  f32x4 acc[4][4];
#pragma unroll
  for (int i = 0; i < 4; ++i)
#pragma unroll
    for (int j = 0; j < 4; ++j) acc[i][j] = f32x4{0.f, 0.f, 0.f, 0.f};

  for (int ks = 0; ks < GK; ks += 64) {
    __syncthreads();  // previous tile's LDS reads done
    for (int c = w; c < 16; c += 4) {
      int r = c * 8 + (lane >> 3);
      int j = lane & 7;
      int sj = j ^ (r & 7);
      gl_lds16((const char*)(X + (size_t)(m0 + r) * GK + ks) + sj * 16, As + c * 1024);
      gl_lds16((const char*)(W + (size_t)(n0 + r) * GK + ks) + sj * 16, Bs + c * 1024);
    }
    __syncthreads();
#pragma unroll
    for (int ksub = 0; ksub < 2; ++ksub) {
      bf16x8 af[4], bfr[4];
#pragma unroll
      for (int mf = 0; mf < 4; ++mf) {
        int r = wm + mf * 16 + l15;
        int j16 = ksub * 4 + l4;
        af[mf] = *(const bf16x8*)(As + r * 128 + ((j16 ^ (r & 7)) * 16));
      }
#pragma unroll
      for (int nf = 0; nf < 4; ++nf) {
        int r = wn + nf * 16 + l15;
        int j16 = ksub * 4 + l4;
        bfr[nf] = *(const bf16x8*)(Bs + r * 128 + ((j16 ^ (r & 7)) * 16));
      }
#pragma unroll
      for (int mf = 0; mf < 4; ++mf)
#pragma unroll
        for (int nf = 0; nf < 4; ++nf) acc[mf][nf] = mfma16(af[mf], bfr[nf], acc[mf][nf]);
    }
  }

  // epilogue: C[m][n], row = 4*l4 + reg, col = l15 (verified layout)
  if (mode == 2) {
    // V projection -> VT [B][H][DH][L]: b=m>>11, l=m&2047, h=n>>6, dh=n&63
    u16* base = (u16*)g.out[z];
#pragma unroll
    for (int nf = 0; nf < 4; ++nf) {
      int n = n0 + wn + nf * 16 + l15;
      float bv = bias[n];
#pragma unroll
      for (int mf = 0; mf < 4; ++mf) {
        int m = m0 + wm + mf * 16 + l4 * 4;  // r spans m..m+3 (consecutive l)
        u16x4 pk;
#pragma unroll
        for (int r = 0; r < 4; ++r) pk[r] = f2bf((acc[mf][nf][r] + bv) * alpha);
        size_t off = (((size_t)(m >> 11) * H_ + (n >> 6)) * DH_ + (n & 63)) * (size_t)L_ + (m & 2047);
        *(u16x4*)(base + off) = pk;
      }
    }
  } else {
#pragma unroll
    for (int nf = 0; nf < 4; ++nf) {
      int n = n0 + wn + nf * 16 + l15;
      float bv = bias[n];
#pragma unroll
      for (int mf = 0; mf < 4; ++mf) {
#pragma unroll
        for (int r = 0; r < 4; ++r) {
          int m = m0 + wm + mf * 16 + l4 * 4 + r;
          float val = (acc[mf][nf][r] + bv) * alpha;
          if (mode == 1)
            ((float*)g.out[z])[(size_t)m * GN + n] = val;
          else
            ((u16*)g.out[z])[(size_t)m * GN + n] = f2bf(val);
        }
      }
    }
  }
}

// ---------------------------------------------------------------- fused attention
// Per (b,h,64-row q-tile): pass1 per-lane-local online max/sum (merged across
// lanes once at the end), pass2 recomputes S, writes normalized P (f32,
// nontemporal) and accumulates ctx = P @ V via MFMA (V pre-transposed).
// K (and K+V in pass 2) are double-buffered in LDS: stage(next) || compute(cur),
// one barrier per tile.
__global__ __launch_bounds__(256) void attn_kernel(const u16* Qp, const u16* Kp,
                                                   const u16* VT, float* attn,
                                                   u16* ctx) {
  const int q0 = blockIdx.x * 64;
  const int h = blockIdx.y, b = blockIdx.z;
  const int tid = threadIdx.x, lane = tid & 63, w = tid >> 6;
  const int l15 = lane & 15, l4 = lane >> 4;
  const int lr = lane >> 3, lj = lane & 7;  // staging decomposition

  __shared__ __align__(16) char smem[48 * 1024];
  char* Qs = smem;           // 8KB
  char* Ps = smem + 8192;    // 8KB (per-wave private rows)
  // K buffers at 16KB + (buf<<13); V buffers at 32KB + (buf<<13)

  const u16* Qbase = Qp + ((size_t)(b * L_ + q0) * D_MODEL_ + h * DH_);
  const u16* Kbase = Kp + ((size_t)(b * L_) * D_MODEL_ + h * DH_);
  const u16* VTb = VT + ((size_t)((b * H_ + h) * DH_) * L_);
  float* attnb = attn + ((size_t)(b * H_ + h)) * L_ * L_;

  auto stK = [&](int t) {
    const int c0 = t * 64, bsel = (t & 1) << 13;
    for (int c = w; c < 8; c += 4) {
      int r = c * 8 + lr, sj = lj ^ (r & 7);
      gl_lds16((const char*)(Kbase + (size_t)(c0 + r) * D_MODEL_) + sj * 16,
               smem + 16384 + bsel + c * 1024);
    }
  };
  auto stV = [&](int t) {
    const int c0 = t * 64, bsel = (t & 1) << 13;
    for (int c = w; c < 8; c += 4) {
      int r = c * 8 + lr, sj = lj ^ (r & 7);
      gl_lds16((const char*)(VTb + (size_t)r * L_ + c0) + sj * 16,
               smem + 32768 + bsel + c * 1024);
    }
  };

  // prologue: stage Q tile + first K tile
  for (int c = w; c < 8; c += 4) {
    int r = c * 8 + lr, sj = lj ^ (r & 7);
    gl_lds16((const char*)(Qbase + (size_t)r * D_MODEL_) + sj * 16, Qs + c * 1024);
  }
  stK(0);
  __syncthreads();

  // hoist this wave's Q A-fragments (rows 16w..16w+15)
  bf16x8 qa[2];
#pragma unroll
  for (int ksub = 0; ksub < 2; ++ksub) {
    int r = w * 16 + l15;
    int j16 = ksub * 4 + l4;
    qa[ksub] = *(const bf16x8*)(Qs + r * 128 + ((j16 ^ (r & 7)) * 16));
  }

  float mloc[4], sloc[4];
#pragma unroll
  for (int r = 0; r < 4; ++r) { mloc[r] = -3.0e38f; sloc[r] = 0.f; }

  // ---- pass 1: per-lane-local online max+sum (no cross-lane per tile)
  for (int t = 0; t < 32; ++t) {
    if (t < 31) stK(t + 1);
    const char* Ks = smem + 16384 + ((t & 1) << 13);
    f32x4 s[4];
#pragma unroll
    for (int nf = 0; nf < 4; ++nf) s[nf] = f32x4{0.f, 0.f, 0.f, 0.f};
    __builtin_amdgcn_s_setprio(1);
#pragma unroll
    for (int ksub = 0; ksub < 2; ++ksub) {
      int j16 = ksub * 4 + l4;
      bf16x8 kb[4];
#pragma unroll
      for (int nf = 0; nf < 4; ++nf) {
        int r = nf * 16 + l15;
        kb[nf] = *(const bf16x8*)(Ks + r * 128 + ((j16 ^ (r & 7)) * 16));
      }
#pragma unroll
      for (int nf = 0; nf < 4; ++nf) s[nf] = mfma16(qa[ksub], kb[nf], s[nf]);
    }
    __builtin_amdgcn_s_setprio(0);
#pragma unroll
    for (int r = 0; r < 4; ++r) {
      float v0 = s[0][r], v1 = s[1][r], v2 = s[2][r], v3 = s[3][r];
      float m4 = fmaxf(fmaxf(v0, v1), fmaxf(v2, v3));
      float mn = fmaxf(mloc[r], m4);
      float es = __expf(v0 - mn) + __expf(v1 - mn) + __expf(v2 - mn) + __expf(v3 - mn);
      sloc[r] = sloc[r] * __expf(mloc[r] - mn) + es;
      mloc[r] = mn;
    }
    __syncthreads();
  }

  // stage pass-2 first tile, overlap with the cross-lane merge
  stK(0);
  stV(0);

  // merge (m,s) across the 16-lane col group; c = m + ln(sum)
  float c_[4];
#pragma unroll
  for (int r = 0; r < 4; ++r) {
    float m = mloc[r], ssum = sloc[r];
#pragma unroll
    for (int d = 1; d < 16; d <<= 1) {
      float mo = __shfl_xor(m, d);
      float so = __shfl_xor(ssum, d);
      float mn = fmaxf(m, mo);
      ssum = ssum * __expf(m - mn) + so * __expf(mo - mn);
      m = mn;
    }
    c_[r] = m + __logf(ssum);
  }

  f32x4 cacc[4];
#pragma unroll
  for (int i = 0; i < 4; ++i) cacc[i] = f32x4{0.f, 0.f, 0.f, 0.f};
  __syncthreads();

  // ---- pass 2: recompute S, write P, accumulate PV
  for (int t = 0; t < 32; ++t) {
    if (t < 31) { stK(t + 1); stV(t + 1); }
    const char* Ks = smem + 16384 + ((t & 1) << 13);
    const char* Vs = smem + 32768 + ((t & 1) << 13);
    const int c0 = t * 64;
    f32x4 s[4];
#pragma unroll
    for (int nf = 0; nf < 4; ++nf) s[nf] = f32x4{0.f, 0.f, 0.f, 0.f};
    __builtin_amdgcn_s_setprio(1);
#pragma unroll
    for (int ksub = 0; ksub < 2; ++ksub) {
      int j16 = ksub * 4 + l4;
      bf16x8 kb[4];
#pragma unroll
      for (int nf = 0; nf < 4; ++nf) {
        int r = nf * 16 + l15;
        kb[nf] = *(const bf16x8*)(Ks + r * 128 + ((j16 ^ (r & 7)) * 16));
      }
#pragma unroll
      for (int nf = 0; nf < 4; ++nf) s[nf] = mfma16(qa[ksub], kb[nf], s[nf]);
    }
    __builtin_amdgcn_s_setprio(0);
    // P = exp(S - c); write f32 to d_out (streaming) and bf16 to LDS
#pragma unroll
    for (int nf = 0; nf < 4; ++nf) {
#pragma unroll
      for (int r = 0; r < 4; ++r) {
        int row = w * 16 + l4 * 4 + r;
        int col = nf * 16 + l15;
        float p = __expf(s[nf][r] - c_[r]);
        __builtin_nontemporal_store(p, attnb + (size_t)(q0 + row) * L_ + c0 + col);
        *(u16*)(Ps + row * 128 + ((((col >> 3) ^ (row & 7))) * 16) + (col & 7) * 2) =
            f2bf(p);
      }
    }
    // PV: ctx[q][d] += sum_kk P[q][kk] * VT[d][kk]
    __builtin_amdgcn_s_setprio(1);
#pragma unroll
    for (int ksub = 0; ksub < 2; ++ksub) {
      int j16 = ksub * 4 + l4;
      int rr = w * 16 + l15;
      bf16x8 pa = *(const bf16x8*)(Ps + rr * 128 + ((j16 ^ (rr & 7)) * 16));
#pragma unroll
      for (int df = 0; df < 4; ++df) {
        int r = df * 16 + l15;
        bf16x8 vb = *(const bf16x8*)(Vs + r * 128 + ((j16 ^ (r & 7)) * 16));
        cacc[df] = mfma16(pa, vb, cacc[df]);
      }
    }
    __builtin_amdgcn_s_setprio(0);
    __syncthreads();
  }

  // ctx write (bf16)
#pragma unroll
  for (int df = 0; df < 4; ++df) {
#pragma unroll
    for (int r = 0; r < 4; ++r) {
      int row = q0 + w * 16 + l4 * 4 + r;
      int col = h * DH_ + df * 16 + l15;
      ctx[(size_t)(b * L_ + row) * D_MODEL_ + col] = f2bf(cacc[df][r]);
    }
  }
}

// ---------------------------------------------------------------- launch
extern "C" void kernel_launch(void* const* d_in, const int* in_sizes, int n_in,
                              void* d_out, int out_size, void* d_ws, size_t ws_size,
                              hipStream_t stream) {
  const float* q = (const float*)d_in[0];
  const float* k = (const float*)d_in[1];
  const float* v = (const float*)d_in[2];
  const float* w_q = (const float*)d_in[3];
  const float* b_q = (const float*)d_in[4];
  const float* w_k = (const float*)d_in[5];
  const float* b_k = (const float*)d_in[6];
  const float* w_v = (const float*)d_in[7];
  const float* b_v = (const float*)d_in[8];
  const float* w_o = (const float*)d_in[9];
  const float* b_o = (const float*)d_in[10];

  float* out = (float*)d_out;
  float* attn = (float*)d_out + (size_t)B_ * L_ * D_MODEL_;

  const size_t MB = 1u << 20;
  char* ws = (char*)d_ws;
  u16* qb = (u16*)(ws + 0 * MB);
  u16* kb = (u16*)(ws + 8 * MB);    // reused as ctx after QKV GEMM
  u16* vb = (u16*)(ws + 16 * MB);
  u16* wqb = (u16*)(ws + 24 * MB);
  u16* wkb = (u16*)(ws + 26 * MB);
  u16* wvb = (u16*)(ws + 28 * MB);
  u16* wob = (u16*)(ws + 30 * MB);
  u16* Qp = (u16*)(ws + 32 * MB);
  u16* Kp = (u16*)(ws + 40 * MB);
  u16* VT = (u16*)(ws + 48 * MB);
  u16* ctx = kb;

  // 1. cast everything to bf16
  CastArgs ca;
  ca.src[0] = q;   ca.dst[0] = qb;  ca.n8[0] = (B_ * L_ * D_MODEL_) / 8;
  ca.src[1] = k;   ca.dst[1] = kb;  ca.n8[1] = (B_ * L_ * D_MODEL_) / 8;
  ca.src[2] = v;   ca.dst[2] = vb;  ca.n8[2] = (B_ * L_ * D_MODEL_) / 8;
  ca.src[3] = w_q; ca.dst[3] = wqb; ca.n8[3] = (D_MODEL_ * D_MODEL_) / 8;
  ca.src[4] = w_k; ca.dst[4] = wkb; ca.n8[4] = (D_MODEL_ * D_MODEL_) / 8;
  ca.src[5] = w_v; ca.dst[5] = wvb; ca.n8[5] = (D_MODEL_ * D_MODEL_) / 8;
  ca.src[6] = w_o; ca.dst[6] = wob; ca.n8[6] = (D_MODEL_ * D_MODEL_) / 8;
  cast_kernel<<<dim3(1024, 1, 7), 256, 0, stream>>>(ca);

  // 2. QKV projections (scale 1/8 folded into Q; V writes VT directly)
  GemmArgs ga;
  ga.X[0] = qb;  ga.W[0] = wqb; ga.bias[0] = b_q; ga.out[0] = Qp; ga.alpha[0] = 0.125f; ga.mode[0] = 0;
  ga.X[1] = kb;  ga.W[1] = wkb; ga.bias[1] = b_k; ga.out[1] = Kp; ga.alpha[1] = 1.f;    ga.mode[1] = 0;
  ga.X[2] = vb;  ga.W[2] = wvb; ga.bias[2] = b_v; ga.out[2] = VT; ga.alpha[2] = 1.f;    ga.mode[2] = 2;
  gemm_bt<<<dim3(8, 32, 3), 256, 0, stream>>>(ga);

  // 3. fused attention: attn out + ctx
  attn_kernel<<<dim3(32, 16, 2), 256, 0, stream>>>(Qp, Kp, VT, attn, ctx);

  // 4. output projection (f32 out + bias)
  GemmArgs go;
  go.X[0] = ctx; go.W[0] = wob; go.bias[0] = b_o; go.out[0] = out; go.alpha[0] = 1.f; go.mode[0] = 1;
  go.X[1] = ctx; go.W[1] = wob; go.bias[1] = b_o; go.out[1] = out; go.alpha[1] = 1.f; go.mode[1] = 1;
  go.X[2] = ctx; go.W[2] = wob; go.bias[2] = b_o; go.out[2] = out; go.alpha[2] = 1.f; go.mode[2] = 1;
  gemm_bt<<<dim3(8, 32, 1), 256, 0, stream>>>(go);
}